// Round 5
// baseline (71.416 us; speedup 1.0000x reference)
//
#include <hip/hip_runtime.h>

// LocalMean: 5x5 box filter, stride 1, reflect padding (edge not duplicated).
// Input/Output: float32, (16, 3, 1024, 1024).
// R1: 122us @ 2.2TB/s, Occ 45%.
// R3: RS=16 + nt stores -> 70.6us, Occ 68%. HBM/replay ~319MB (FETCH 118 +
//     WRITE 201), 4.56 TB/s effective.
// R4: exact-fill 2048 blocks -> 70.0us, NO change. Not occupancy-bound.
// R5: depth-1 software pipeline: issue row y+3's loads before computing/
//     storing row y, so HBM latency hides under compute (the dynamic-bound
//     inner loop prevented the compiler from doing this itself).

typedef float f32x4 __attribute__((ext_vector_type(4)));

constexpr int W       = 1024;
constexpr int H       = 1024;
constexpr int NPLANES = 16 * 3;
constexpr int RPB     = 24;                        // output rows per block
constexpr int NBLK    = (NPLANES * H) / RPB;       // 2048 exactly

struct RowRaw { f32x4 v, lv, rv; };

__global__ __launch_bounds__(256, 8)   // 8 blocks/CU -> 32 waves/CU
void box5_kernel(const float* __restrict__ in, float* __restrict__ out) {
    const int t  = threadIdx.x;        // 0..255, covers full row: 4 px each
    const int x0 = t << 2;
    // Safe (always in-bounds, 16B-aligned) neighbor-chunk offsets; edge
    // threads get a dummy load whose lanes are overridden by reflect selects.
    const int lx = (t != 0)   ? x0 - 4 : x0;
    const int rx = (t != 255) ? x0 + 4 : x0;
    const float inv25 = 1.0f / 25.0f;

    auto load_row = [&](const float* img, int r) -> RowRaw {
        const int rr = (r < 0) ? -r : ((r >= H) ? 2 * H - 2 - r : r);  // reflect
        const float* row = img + (size_t)rr * W;
        RowRaw rw;
        rw.v  = *(const f32x4*)(row + x0);
        rw.lv = *(const f32x4*)(row + lx);
        rw.rv = *(const f32x4*)(row + rx);
        return rw;
    };

    auto hsum = [&](const RowRaw& rw) -> f32x4 {
        const f32x4 v = rw.v;
        // elements x0-2..x0+5 with horizontal reflect at image edges
        const float em2 = (t != 0)   ? rw.lv.z : v.z;   // x=-2 -> 2
        const float em1 = (t != 0)   ? rw.lv.w : v.y;   // x=-1 -> 1
        const float e4  = (t != 255) ? rw.rv.x : v.z;   // x=1024 -> 1022
        const float e5  = (t != 255) ? rw.rv.y : v.y;   // x=1025 -> 1021
        const float c12  = v.y + v.z;
        const float c123 = c12 + v.w;
        f32x4 hn;
        hn.x = (em2 + em1) + v.x + c12;
        hn.y = em1 + v.x + c123;
        hn.z = (v.x + c123) + e4;
        hn.w = c123 + (e4 + e5);
        return hn;
    };

    int g         = blockIdx.x * RPB;  // flattened global output row
    int rows_left = RPB;

    while (rows_left > 0) {
        const int plane = g >> 10;           // g / H
        const int r0    = g & (H - 1);       // g % H
        int seg = H - r0; if (seg > rows_left) seg = rows_left;

        const size_t poff = (size_t)plane * (size_t)(W * H);
        const float* img = in  + poff;
        float*       o   = out + poff;

        // Prologue: h-window for rows r0-2..r0+1; all 12 loads issue together.
        RowRaw a = load_row(img, r0 - 2);
        RowRaw b = load_row(img, r0 - 1);
        RowRaw c = load_row(img, r0);
        RowRaw d = load_row(img, r0 + 1);
        f32x4 h0 = (f32x4)(0.f);
        f32x4 h1 = hsum(a), h2 = hsum(b), h3 = hsum(c), h4 = hsum(d);

        // Preload row r0+2 (consumed at y=r0).
        RowRaw cur = load_row(img, r0 + 2);

        for (int y = r0; y < r0 + seg; ++y) {
            // Issue next row's loads BEFORE touching cur: one row-load always
            // in flight per wave while we compute. (y+3 is reflect-safe.)
            RowRaw nxt = load_row(img, y + 3);

            const f32x4 hn = hsum(cur);
            h0 = h1; h1 = h2; h2 = h3; h3 = h4; h4 = hn;

            f32x4 s = ((h0 + h1) + (h2 + h3)) + h4;
            s *= inv25;
            __builtin_nontemporal_store(s, (f32x4*)(o + (size_t)y * W + x0));

            cur = nxt;
        }

        g += seg; rows_left -= seg;
    }
}

extern "C" void kernel_launch(void* const* d_in, const int* in_sizes, int n_in,
                              void* d_out, int out_size, void* d_ws, size_t ws_size,
                              hipStream_t stream) {
    const float* in  = (const float*)d_in[0];
    float*       out = (float*)d_out;

    box5_kernel<<<dim3(NBLK), dim3(256), 0, stream>>>(in, out);
}

// Round 6
// 71.343 us; speedup vs baseline: 1.0010x; 1.0010x over previous
//
#include <hip/hip_runtime.h>

// LocalMean: 5x5 box filter, stride 1, reflect padding (edge not duplicated).
// Input/Output: float32, (16, 3, 1024, 1024).
// R1: 122us @ 2.2TB/s, Occ 45%.
// R3: RS=16 + nt stores -> 70.6us, Occ 68%. ~319MB/replay -> 4.6 TB/s.
// R4: exact-fill 2048 blocks -> 70.0us, null. Not occupancy-bound.
// R5: depth-1 SW pipeline -> 71.4us, null (VGPR=28: compiler collapsed it).
//     Pipe budgets: VALU ~5us, VMEM-issue ~6-20us, HBM ~51us -> memory-bound
//     at 72% of copy ceiling.
// R6: kill 3x read-request amplification: one dwordx4 load per thread-row;
//     halo via __shfl_up/__shfl_down(width 64); cross-wave halo via
//     exec-masked 8B loads on lane 0/63 only. L1 read bytes 3x down, HBM
//     unchanged. If null -> at mixed-stream HBM ceiling, declare roofline.

typedef float f32x4 __attribute__((ext_vector_type(4)));
typedef float f32x2 __attribute__((ext_vector_type(2)));

constexpr int W       = 1024;
constexpr int H       = 1024;
constexpr int NPLANES = 16 * 3;
constexpr int RPB     = 24;                        // output rows per block
constexpr int NBLK    = (NPLANES * H) / RPB;       // 2048 exactly

__global__ __launch_bounds__(256, 8)   // 8 blocks/CU -> 32 waves/CU
void box5_kernel(const float* __restrict__ in, float* __restrict__ out) {
    const int t    = threadIdx.x;      // 0..255, covers full row: 4 px each
    const int lane = t & 63;
    const int x0   = t << 2;
    const float inv25 = 1.0f / 25.0f;

    const bool lo_lane = (lane == 0);   // needs left cross-wave halo
    const bool hi_lane = (lane == 63);  // needs right cross-wave halo
    // Safe in-bounds addresses for the masked halo loads (t==0/255 get a
    // dummy self-load whose lanes are overridden by reflect selects).
    const int lx2 = (t != 0)   ? x0 - 2 : x0;   // 8B-aligned
    const int rx2 = (t != 255) ? x0 + 4 : x0;

    int g         = blockIdx.x * RPB;  // flattened global output row
    int rows_left = RPB;

    while (rows_left > 0) {
        const int plane = g >> 10;           // g / H
        const int r0    = g & (H - 1);       // g % H
        int seg = H - r0; if (seg > rows_left) seg = rows_left;

        const size_t poff = (size_t)plane * (size_t)(W * H);
        const float* img = in  + poff;
        float*       o   = out + poff;

        f32x4 h0 = (f32x4)(0.f);
        f32x4 h1 = h0, h2 = h0, h3 = h0, h4 = h0;

        for (int cnt = 0; cnt < seg + 4; ++cnt) {
            const int r  = r0 - 2 + cnt;                                  // virtual input row
            const int rr = (r < 0) ? -r : ((r >= H) ? 2 * H - 2 - r : r); // reflect
            const float* row = img + (size_t)rr * W;

            const f32x4 v = *(const f32x4*)(row + x0);

            // cross-wave halo: one 8B exec-masked load on lane 0 / lane 63
            f32x2 le = (f32x2)(0.f), re = (f32x2)(0.f);
            if (lo_lane) le = *(const f32x2*)(row + lx2);
            if (hi_lane) re = *(const f32x2*)(row + rx2);

            // in-wave halo via shuffles (width 64)
            float em2 = __shfl_up(v.z, 1, 64);     // row[x0-2]
            float em1 = __shfl_up(v.w, 1, 64);     // row[x0-1]
            float e4  = __shfl_down(v.x, 1, 64);   // row[x0+4]
            float e5  = __shfl_down(v.y, 1, 64);   // row[x0+5]

            if (lo_lane) {
                em2 = (t == 0) ? v.z : le.x;       // reflect: x=-2 -> 2
                em1 = (t == 0) ? v.y : le.y;       // reflect: x=-1 -> 1
            }
            if (hi_lane) {
                e4 = (t == 255) ? v.z : re.x;      // reflect: 1024 -> 1022
                e5 = (t == 255) ? v.y : re.y;      // reflect: 1025 -> 1021
            }

            // 4 horizontal 5-tap sums, sharing partials
            const float c12  = v.y + v.z;
            const float c123 = c12 + v.w;
            f32x4 hn;
            hn.x = (em2 + em1) + v.x + c12;
            hn.y = em1 + v.x + c123;
            hn.z = (v.x + c123) + e4;
            hn.w = c123 + (e4 + e5);

            // rotate 5-row window
            h0 = h1; h1 = h2; h2 = h3; h3 = h4; h4 = hn;

            if (cnt >= 4) {
                const int y = r - 2;                      // output row
                f32x4 s = ((h0 + h1) + (h2 + h3)) + h4;
                s *= inv25;
                __builtin_nontemporal_store(s, (f32x4*)(o + (size_t)y * W + x0));
            }
        }

        g += seg; rows_left -= seg;
    }
}

extern "C" void kernel_launch(void* const* d_in, const int* in_sizes, int n_in,
                              void* d_out, int out_size, void* d_ws, size_t ws_size,
                              hipStream_t stream) {
    const float* in  = (const float*)d_in[0];
    float*       out = (float*)d_out;

    box5_kernel<<<dim3(NBLK), dim3(256), 0, stream>>>(in, out);
}

// Round 8
// 69.357 us; speedup vs baseline: 1.0297x; 1.0286x over previous
//
#include <hip/hip_runtime.h>

// LocalMean: 5x5 box filter, stride 1, reflect padding (edge not duplicated).
// Input/Output: float32, (16, 3, 1024, 1024).
// R1: 122us @ 2.2TB/s, Occ 45% (1536 blocks).
// R3: RS=16 + builtin-nt stores -> 70.6us, Occ 68%.
// R4: exact-fill 2048 blocks, RPB=24 -> 70.0us (best). Not occupancy-bound.
// R5: depth-1 SW pipeline -> null. R6: shuffle-halo (1 load/row) -> null.
// R7: inline-asm sc0/sc1/nt store bypass -> BROKE correctness (L2 dirty-line
//     coherence with host readback). Write-allocation not shader-steerable.
// Conclusion: memory-bound. 398MB logical traffic / 70us = 5.7 TB/s logical
//   = 91% of the 6.29 TB/s float4-copy ceiling; residual = reflect-halo
//   re-reads + 37:63 R:W channel mix. This is the R4 known-good kernel.

typedef float f32x4 __attribute__((ext_vector_type(4)));

constexpr int W       = 1024;
constexpr int H       = 1024;
constexpr int NPLANES = 16 * 3;
constexpr int RPB     = 24;                        // output rows per block
constexpr int NBLK    = (NPLANES * H) / RPB;       // 2048 exactly

__global__ __launch_bounds__(256, 8)   // 8 blocks/CU -> 32 waves/CU
void box5_kernel(const float* __restrict__ in, float* __restrict__ out) {
    const int t  = threadIdx.x;        // 0..255, covers full row: 4 px each
    const int x0 = t << 2;
    // Safe (always in-bounds, 16B-aligned) neighbor-chunk offsets; edge
    // threads get a dummy load whose lanes are overridden by reflect selects.
    const int lx = (t != 0)   ? x0 - 4 : x0;
    const int rx = (t != 255) ? x0 + 4 : x0;
    const float inv25 = 1.0f / 25.0f;

    int g         = blockIdx.x * RPB;  // flattened global output row
    int rows_left = RPB;

    while (rows_left > 0) {
        const int plane = g >> 10;           // g / H
        const int r0    = g & (H - 1);       // g % H
        int seg = H - r0; if (seg > rows_left) seg = rows_left;

        const size_t poff = (size_t)plane * (size_t)(W * H);
        const float* img = in  + poff;
        float*       o   = out + poff;

        f32x4 h0 = (f32x4)(0.f);
        f32x4 h1 = h0, h2 = h0, h3 = h0, h4 = h0;

        for (int cnt = 0; cnt < seg + 4; ++cnt) {
            const int r  = r0 - 2 + cnt;                                  // virtual input row
            const int rr = (r < 0) ? -r : ((r >= H) ? 2 * H - 2 - r : r); // reflect
            const float* row = img + (size_t)rr * W;

            const f32x4 v  = *(const f32x4*)(row + x0);
            const f32x4 lv = *(const f32x4*)(row + lx);
            const f32x4 rv = *(const f32x4*)(row + rx);

            // elements x0-2..x0+5 with horizontal reflect at image edges
            const float em2 = (t != 0)   ? lv.z : v.z;   // x=-2 -> 2
            const float em1 = (t != 0)   ? lv.w : v.y;   // x=-1 -> 1
            const float e4  = (t != 255) ? rv.x : v.z;   // x=1024 -> 1022
            const float e5  = (t != 255) ? rv.y : v.y;   // x=1025 -> 1021

            // 4 horizontal 5-tap sums, sharing partials
            const float c12  = v.y + v.z;
            const float c123 = c12 + v.w;
            f32x4 hn;
            hn.x = (em2 + em1) + v.x + c12;
            hn.y = em1 + v.x + c123;
            hn.z = (v.x + c123) + e4;
            hn.w = c123 + (e4 + e5);

            // rotate 5-row window
            h0 = h1; h1 = h2; h2 = h3; h3 = h4; h4 = hn;

            if (cnt >= 4) {
                const int y = r - 2;                      // output row
                f32x4 s = ((h0 + h1) + (h2 + h3)) + h4;
                s *= inv25;
                __builtin_nontemporal_store(s, (f32x4*)(o + (size_t)y * W + x0));
            }
        }

        g += seg; rows_left -= seg;
    }
}

extern "C" void kernel_launch(void* const* d_in, const int* in_sizes, int n_in,
                              void* d_out, int out_size, void* d_ws, size_t ws_size,
                              hipStream_t stream) {
    const float* in  = (const float*)d_in[0];
    float*       out = (float*)d_out;

    box5_kernel<<<dim3(NBLK), dim3(256), 0, stream>>>(in, out);
}